// Round 15
// baseline (3118.035 us; speedup 1.0000x reference)
//
#include <hip/hip_runtime.h>
#include <math.h>

// Problem constants
constexpr int CVOC = 100;
constexpr int NCLS = 18;
constexpr int EE   = 512;   // word emb
constexpr int HHm  = 512;   // main GRU hidden
constexpr int CEc  = 128;   // char emb
constexpr int CHc  = 256;   // char GRU hidden
constexpr int BB   = 64;
constexpr int TT   = 64;
constexpr int CCh  = 16;    // chars per word
constexpr int NTOK = BB*TT;       // 4096
constexpr int G3C  = 3*CHc;       // 768
constexpr int G3H  = 3*HHm;       // 1536
constexpr int KIN  = EE + CHc;    // 768

typedef __attribute__((ext_vector_type(8))) short bf16x8;
typedef __attribute__((ext_vector_type(4))) float f32x4;

__device__ __forceinline__ float sigmoidf_(float x){ return 1.0f/(1.0f + __expf(-x)); }
__device__ __forceinline__ float tanhf_(float x){ return 1.0f - 2.0f/(__expf(2.0f*x) + 1.0f); }
__device__ __forceinline__ unsigned short f2bf(float x){
  unsigned int u = __float_as_uint(x);
  unsigned int r = (u + 0x7FFFu + ((u>>16)&1u)) >> 16;
  return (unsigned short)r;
}

// ---------------------------------------------------------------------------
// K1: char input-projection table U2[c][g] (f32, biases folded; +bhh for r,z)
__global__ void k_uchar(const float* __restrict__ cemb, const float* __restrict__ wih,
                        const float* __restrict__ bih, const float* __restrict__ bhh,
                        float* __restrict__ U2){
  const int c = blockIdx.x;
  const int g = threadIdx.x;
  const float* a = cemb + (size_t)c*CEc;
  const float* w = wih  + (size_t)g*CEc;
  float s = 0.f;
  for(int k=0;k<CEc;k++) s = fmaf(a[k], w[k], s);
  s += bih[g];
  if(g < 2*CHc) s += bhh[g];
  U2[(size_t)c*G3C + g] = s;
}

// ---------------------------------------------------------------------------
// generic transpose: in[R][C] -> out[C][R]
__global__ void k_transpose(const float* __restrict__ in, float* __restrict__ out,
                            int R, int C){
  int idx = blockIdx.x*blockDim.x + threadIdx.x;
  if(idx >= R*C) return;
  int k = idx / R;
  int j = idx % R;
  out[idx] = in[(size_t)j*C + k];
}

// ---------------------------------------------------------------------------
// f32 -> bf16 (RNE)
__global__ void k_w2bf(const float* __restrict__ in, unsigned short* __restrict__ out,
                       int n){
  int i = blockIdx.x*256 + threadIdx.x;
  if(i < n) out[i] = f2bf(in[i]);
}

// ---------------------------------------------------------------------------
// K2 v8: char GRU, bf16 MFMA, direct per-thread U2 loads (unchanged).
__global__ __launch_bounds__(1024, 1) void k_chargru(
    const int* __restrict__ chars, const float* __restrict__ U2,
    const unsigned short* __restrict__ Wb, const float* __restrict__ bhh,
    float* __restrict__ char_h){
  __shared__ unsigned short hb[16][280];   // 9KB bf16 h
  __shared__ int chs_all[16][16];          // 1KB [w][t]
  const int tid  = threadIdx.x;
  const int lane = tid & 63;
  const int wv   = tid >> 6;        // 0..15
  const int la   = lane & 15;
  const int lb   = lane >> 4;       // 0..3
  const int w0   = blockIdx.x * 16;
  const int c    = wv*16 + la;      // this thread's h-column (0..255)
  bf16x8 wreg[2][8];
  #pragma unroll
  for(int g=0; g<2; g++){
    const int gcol = g*CHc + c;
    #pragma unroll
    for(int ks=0; ks<8; ks++)
      wreg[g][ks] = *reinterpret_cast<const bf16x8*>(
          &Wb[(size_t)gcol*CHc + ks*32 + lb*8]);
  }
  const unsigned short* wnp = &Wb[(size_t)(2*CHc + c)*CHc + lb*8];  // n-gate row
  const float bhn = bhh[2*CHc + c];
  float hfr[4];
  #pragma unroll
  for(int i=0;i<4;i++) hfr[i]=0.f;
  for(int f=tid; f<16*280; f+=1024) (&hb[0][0])[f] = 0;
  if(tid < 256) chs_all[tid>>4][tid&15] = chars[(size_t)(w0 + (tid>>4))*CCh + (tid&15)];
  __syncthreads();

  for(int t=0; t<CCh; t++){
    float u2v[4][3];
    #pragma unroll
    for(int i=0;i<4;i++){
      const int ch = chs_all[lb*4 + i][t];
      const float* urow = U2 + (size_t)ch*G3C;
      u2v[i][0] = urow[c];
      u2v[i][1] = urow[CHc + c];
      u2v[i][2] = urow[2*CHc + c];
    }
    f32x4 acc[3];
    #pragma unroll
    for(int g=0;g<3;g++) acc[g] = (f32x4){0.f,0.f,0.f,0.f};
    {
      bf16x8 wn[4];
      #pragma unroll
      for(int q=0;q<4;q++)
        wn[q] = *reinterpret_cast<const bf16x8*>(wnp + q*32);
      #pragma unroll
      for(int ks=0; ks<4; ks++){
        bf16x8 a = *reinterpret_cast<const bf16x8*>(&hb[la][ks*32 + lb*8]);
        acc[0] = __builtin_amdgcn_mfma_f32_16x16x32_bf16(a, wreg[0][ks], acc[0], 0,0,0);
        acc[1] = __builtin_amdgcn_mfma_f32_16x16x32_bf16(a, wreg[1][ks], acc[1], 0,0,0);
        acc[2] = __builtin_amdgcn_mfma_f32_16x16x32_bf16(a, wn[ks],      acc[2], 0,0,0);
      }
      #pragma unroll
      for(int q=0;q<4;q++)
        wn[q] = *reinterpret_cast<const bf16x8*>(wnp + (4+q)*32);
      #pragma unroll
      for(int ks=4; ks<8; ks++){
        bf16x8 a = *reinterpret_cast<const bf16x8*>(&hb[la][ks*32 + lb*8]);
        acc[0] = __builtin_amdgcn_mfma_f32_16x16x32_bf16(a, wreg[0][ks], acc[0], 0,0,0);
        acc[1] = __builtin_amdgcn_mfma_f32_16x16x32_bf16(a, wreg[1][ks], acc[1], 0,0,0);
        acc[2] = __builtin_amdgcn_mfma_f32_16x16x32_bf16(a, wn[ks-4],    acc[2], 0,0,0);
      }
    }
    __syncthreads();
    #pragma unroll
    for(int i=0;i<4;i++){
      const int w = lb*4 + i;
      float r = sigmoidf_(u2v[i][0] + acc[0][i]);
      float z = sigmoidf_(u2v[i][1] + acc[1][i]);
      float n = tanhf_   (u2v[i][2] + r*(acc[2][i] + bhn));
      float hn = (1.f - z)*n + z*hfr[i];
      hfr[i] = hn;
      hb[w][c] = f2bf(hn);
    }
    __syncthreads();
  }
  #pragma unroll
  for(int i=0;i<4;i++){
    const int w = lb*4 + i;
    char_h[(size_t)(w0+w)*CHc + c] = hfr[i];
  }
}

// ---------------------------------------------------------------------------
// K3: gx GEMM, f32 (unchanged). gx[token][g], bias folded (+bhh for r,z).
__global__ __launch_bounds__(256) void k_gxmain(
    const int* __restrict__ x, const float* __restrict__ wemb,
    const float* __restrict__ chh, const float* __restrict__ WihT,
    const float* __restrict__ bih, const float* __restrict__ bhh,
    float* __restrict__ gx){
  __shared__ float As[128][20];
  __shared__ float Bs[16][100];
  __shared__ int xs[128];
  const int tid = threadIdx.x;
  const int rb = blockIdx.x * 128;
  const int nb = blockIdx.y * 96;
  if(tid < 128) xs[tid] = x[rb + tid];
  const int tr = tid >> 4, tc = tid & 15;
  float acc[8][6];
  #pragma unroll
  for(int i=0;i<8;i++)
    #pragma unroll
    for(int j=0;j<6;j++) acc[i][j]=0.f;
  __syncthreads();
  for(int kb=0; kb<KIN; kb+=16){
    #pragma unroll
    for(int i=0;i<2;i++){
      int idx = i*256 + tid;
      int m = idx & 127, kq = idx >> 7;
      int k = kb + kq*4;
      float4 v;
      if(k < EE) v = *reinterpret_cast<const float4*>(&wemb[(size_t)xs[m]*EE + k]);
      else       v = *reinterpret_cast<const float4*>(&chh[(size_t)(rb+m)*CHc + (k-EE)]);
      *reinterpret_cast<float4*>(&As[m][kq*4]) = v;
    }
    #pragma unroll
    for(int i=0;i<2;i++){
      int idx = i*256 + tid;
      if(idx < 384){
        int k = idx / 24, n4 = (idx % 24)*4;
        *reinterpret_cast<float4*>(&Bs[k][n4]) =
            *reinterpret_cast<const float4*>(&WihT[(size_t)(kb+k)*G3H + nb + n4]);
      }
    }
    __syncthreads();
    #pragma unroll
    for(int k=0;k<16;k++){
      float a[8];
      #pragma unroll
      for(int i=0;i<4;i++){ a[i]=As[tr*4+i][k]; a[4+i]=As[64+tr*4+i][k]; }
      float2 b0 = *reinterpret_cast<const float2*>(&Bs[k][tc*2]);
      float2 b1 = *reinterpret_cast<const float2*>(&Bs[k][32+tc*2]);
      float2 b2 = *reinterpret_cast<const float2*>(&Bs[k][64+tc*2]);
      float b[6] = {b0.x,b0.y,b1.x,b1.y,b2.x,b2.y};
      #pragma unroll
      for(int i=0;i<8;i++)
        #pragma unroll
        for(int j=0;j<6;j++)
          acc[i][j] = fmaf(a[i], b[j], acc[i][j]);
    }
    __syncthreads();
  }
  #pragma unroll
  for(int i=0;i<8;i++){
    int row = rb + ((i<4) ? tr*4+i : 64 + tr*4 + (i-4));
    #pragma unroll
    for(int j=0;j<6;j++){
      int g = nb + (j>>1)*32 + tc*2 + (j&1);
      float v = acc[i][j] + bih[g] + (g < 2*HHm ? bhh[g] : 0.f);
      gx[(size_t)row*G3H + g] = v;
    }
  }
}

// ---------------------------------------------------------------------------
// K4 v8: main GRU, BATCH-PARALLEL — ZERO inter-block sync.
// Key: GRU recurrence is independent across batch rows. 4 blocks x 16 rows;
// each block runs all 64 steps locally. Per step: [16,512]@[512,1536] bf16
// MFMA (25.2 MFLOP ~= 3.1us on one CU). Wave wv owns j in [wv*32,+32) of ALL
// 3 gates -> 6 MFMA tiles/k-step; D-frag ownership step-invariant ->
// h f32 in registers (8/thread), fully in-register epilogue (chargru scheme).
// Weights streamed from XCD-local L2 (t-invariant addrs, 1.5MB/block/step,
// hidden under MFMA). One barrier/step (double-buffered bf16 h in LDS).
// No atomics/tags/polls; replay-safe by construction.
__global__ __launch_bounds__(1024, 1) void k_grumain(
    const unsigned short* __restrict__ Wbm, const float* __restrict__ gx,
    const float* __restrict__ bhh, float* __restrict__ outh){
  __shared__ unsigned short hb[2][16][520];  // 2 x 16.3KB bf16 h (rows 1040B)
  const int tid  = threadIdx.x;
  const int lane = tid & 63;
  const int wv   = tid >> 6;          // 0..15
  const int la   = lane & 15;
  const int lb   = lane >> 4;         // 0..3
  const int b0   = blockIdx.x * 16;   // batch rows [b0, b0+16)
  // thread's outputs: rows b0+lb*4+i (i 0..3), cols j = wv*32 + q*16 + la (q 0..1)
  float bhn[2];
  #pragma unroll
  for(int q=0;q<2;q++) bhn[q] = bhh[2*HHm + wv*32 + q*16 + la];
  float hfr[4][2];
  #pragma unroll
  for(int i=0;i<4;i++){ hfr[i][0]=0.f; hfr[i][1]=0.f; }
  for(int f=tid; f<16*520; f+=1024) (&hb[0][0][0])[f] = 0;   // h0 = 0
  __syncthreads();
  int cur = 0;
  for(int t=0; t<TT; t++){
    // gx prefetch (24 f32; independent of h)
    float gxv[4][2][3];
    #pragma unroll
    for(int i=0;i<4;i++){
      const size_t tok = (size_t)(b0 + lb*4 + i)*TT + t;
      #pragma unroll
      for(int q=0;q<2;q++){
        const int j = wv*32 + q*16 + la;
        gxv[i][q][0] = gx[tok*G3H +           j];
        gxv[i][q][1] = gx[tok*G3H + HHm +     j];
        gxv[i][q][2] = gx[tok*G3H + 2*HHm +   j];
      }
    }
    // MFMA: 6 tiles x 16 k-steps; weights streamed (L2-hot, t-invariant)
    f32x4 acc[3][2];
    #pragma unroll
    for(int g=0;g<3;g++){ acc[g][0]=(f32x4){0.f,0.f,0.f,0.f}; acc[g][1]=(f32x4){0.f,0.f,0.f,0.f}; }
    #pragma unroll
    for(int ks=0; ks<16; ks++){
      bf16x8 a = *reinterpret_cast<const bf16x8*>(&hb[cur][la][ks*32 + lb*8]);
      #pragma unroll
      for(int g=0;g<3;g++)
        #pragma unroll
        for(int q=0;q<2;q++){
          bf16x8 w = *reinterpret_cast<const bf16x8*>(
              &Wbm[(size_t)(g*HHm + wv*32 + q*16 + la)*HHm + ks*32 + lb*8]);
          acc[g][q] = __builtin_amdgcn_mfma_f32_16x16x32_bf16(a, w, acc[g][q], 0,0,0);
        }
    }
    // in-register epilogue; write next h (bf16) to the OTHER buffer
    const int nxt = cur ^ 1;
    #pragma unroll
    for(int i=0;i<4;i++){
      const int row = lb*4 + i;
      #pragma unroll
      for(int q=0;q<2;q++){
        const int j = wv*32 + q*16 + la;
        float r = sigmoidf_(gxv[i][q][0] + acc[0][q][i]);
        float z = sigmoidf_(gxv[i][q][1] + acc[1][q][i]);
        float n = tanhf_   (gxv[i][q][2] + r*(acc[2][q][i] + bhn[q]));
        float hn = (1.f - z)*n + z*hfr[i][q];
        hfr[i][q] = hn;
        hb[nxt][row][j] = f2bf(hn);
        outh[((size_t)t*BB + b0 + row)*HHm + j] = hn;
      }
    }
    __syncthreads();   // hb[nxt] complete before next step's MFMA reads
    cur = nxt;
  }
}

// ---------------------------------------------------------------------------
// K5: classifier. One block per time-step t; reads outh[t][b][j].
__global__ __launch_bounds__(256) void k_cls(
    const float* __restrict__ outh, const float* __restrict__ clsW,
    const float* __restrict__ clsb, float* __restrict__ out){
  __shared__ float wls[20*HHm];     // 40KB
  __shared__ float hch[64][129];    // 33KB
  const int tid = threadIdx.x;
  const int t = blockIdx.x;
  const int b = tid & 63;
  const int q = tid >> 6;
  const int c0 = q*5;
  for(int f = tid*4; f < 20*HHm; f += 1024){
    float4 v = make_float4(0.f,0.f,0.f,0.f);
    if(f < NCLS*HHm) v = *reinterpret_cast<const float4*>(&clsW[f]);
    *reinterpret_cast<float4*>(&wls[f]) = v;
  }
  float acc[5] = {0.f,0.f,0.f,0.f,0.f};
  for(int kc=0; kc<4; kc++){
    __syncthreads();
    for(int i=0;i<32;i++){
      int f = i*256 + tid;
      int b2 = f >> 7, kk = f & 127;
      hch[b2][kk] = outh[((size_t)t*BB + b2)*HHm + kc*128 + kk];
    }
    __syncthreads();
    for(int k=0;k<128;k++){
      float hv = hch[b][k];
      #pragma unroll
      for(int i=0;i<5;i++)
        acc[i] = fmaf(hv, wls[(size_t)(c0+i)*HHm + kc*128 + k], acc[i]);
    }
  }
  #pragma unroll
  for(int i=0;i<5;i++){
    int cls = c0 + i;
    if(cls < NCLS) out[((size_t)b*TT + t)*NCLS + cls] = acc[i] + clsb[cls];
  }
}

// ---------------------------------------------------------------------------
extern "C" void kernel_launch(void* const* d_in, const int* in_sizes, int n_in,
                              void* d_out, int out_size, void* d_ws, size_t ws_size,
                              hipStream_t stream){
  const int*   x     = (const int*)d_in[0];
  const int*   chars = (const int*)d_in[1];
  const float* wemb  = (const float*)d_in[2];
  const float* cemb  = (const float*)d_in[3];
  const float* cWih  = (const float*)d_in[4];
  const float* cWhh  = (const float*)d_in[5];
  const float* cbih  = (const float*)d_in[6];
  const float* cbhh  = (const float*)d_in[7];
  const float* gWih  = (const float*)d_in[8];
  const float* gWhh  = (const float*)d_in[9];
  const float* gbih  = (const float*)d_in[10];
  const float* gbhh  = (const float*)d_in[11];
  const float* clsW  = (const float*)d_in[12];
  const float* clsb  = (const float*)d_in[13];
  float* out = (float*)d_out;
  float* ws  = (float*)d_ws;

  // workspace layout (floats unless noted)
  float* U2    = ws;                   // 100*768    = 76800
  float* WihTm = U2 + 76800;           // 768*1536   = 1179648
  float* chh   = WihTm + 1179648;      // 4096*256   = 1048576
  float* gx    = chh + 1048576;        // 4096*1536  = 6291456   [token][g]
  float* outh  = gx + 6291456;         // 64*64*512  = 2097152   [t][b][j]
  unsigned short* Wb  = (unsigned short*)(outh + 2097152);  // 768*256 bf16 (char Whh)
  unsigned short* Wbm = Wb + G3C*CHc;                        // 1536*512 bf16 (main Whh)

  k_uchar<<<CVOC, G3C, 0, stream>>>(cemb, cWih, cbih, cbhh, U2);
  k_w2bf<<<(G3C*CHc + 255)/256, 256, 0, stream>>>(cWhh, Wb, G3C*CHc);
  k_w2bf<<<(G3H*HHm + 255)/256, 256, 0, stream>>>(gWhh, Wbm, G3H*HHm);
  k_transpose<<<(G3H*KIN + 255)/256, 256, 0, stream>>>(gWih, WihTm, G3H, KIN);
  k_chargru<<<NTOK/16, 1024, 0, stream>>>(chars, U2, Wb, cbhh, chh);
  k_gxmain<<<dim3(NTOK/128, G3H/96), 256, 0, stream>>>(x, wemb, chh, WihTm, gbih, gbhh, gx);
  k_grumain<<<4, 1024, 0, stream>>>(Wbm, gx, gbhh, outh);
  k_cls<<<TT, 256, 0, stream>>>(outh, clsW, clsb, out);
}

// Round 16
// 451.174 us; speedup vs baseline: 6.9109x; 6.9109x over previous
//
#include <hip/hip_runtime.h>
#include <math.h>

// Problem constants
constexpr int CVOC = 100;
constexpr int NCLS = 18;
constexpr int EE   = 512;   // word emb
constexpr int HHm  = 512;   // main GRU hidden
constexpr int CEc  = 128;   // char emb
constexpr int CHc  = 256;   // char GRU hidden
constexpr int BB   = 64;
constexpr int TT   = 64;
constexpr int CCh  = 16;    // chars per word
constexpr int NTOK = BB*TT;       // 4096
constexpr int G3C  = 3*CHc;       // 768
constexpr int G3H  = 3*HHm;       // 1536
constexpr int KIN  = EE + CHc;    // 768

typedef __attribute__((ext_vector_type(8))) short bf16x8;
typedef __attribute__((ext_vector_type(4))) float f32x4;

__device__ __forceinline__ float sigmoidf_(float x){ return 1.0f/(1.0f + __expf(-x)); }
__device__ __forceinline__ float tanhf_(float x){ return 1.0f - 2.0f/(__expf(2.0f*x) + 1.0f); }
__device__ __forceinline__ unsigned short f2bf(float x){
  unsigned int u = __float_as_uint(x);
  unsigned int r = (u + 0x7FFFu + ((u>>16)&1u)) >> 16;
  return (unsigned short)r;
}

// ---------------------------------------------------------------------------
// K1: char input-projection table, PADDED layout U2p[char][col][4]:
// slot = {r, z, n, pad}; biases folded (+bhh for r,z). One float4/word-col.
__global__ void k_uchar(const float* __restrict__ cemb, const float* __restrict__ wih,
                        const float* __restrict__ bih, const float* __restrict__ bhh,
                        float* __restrict__ U2p){
  const int c = blockIdx.x;        // char 0..99
  const int g = threadIdx.x;       // 0..767 (gate-major row of wih)
  const float* a = cemb + (size_t)c*CEc;
  const float* w = wih  + (size_t)g*CEc;
  float s = 0.f;
  for(int k=0;k<CEc;k++) s = fmaf(a[k], w[k], s);
  s += bih[g];
  if(g < 2*CHc) s += bhh[g];
  const int gate = g >> 8;         // 0..2
  const int col  = g & 255;
  U2p[((size_t)c*256 + col)*4 + gate] = s;
}

// ---------------------------------------------------------------------------
// f32 -> bf16 (RNE)
__global__ void k_w2bf(const float* __restrict__ in, unsigned short* __restrict__ out,
                       int n){
  int i = blockIdx.x*256 + threadIdx.x;
  if(i < n) out[i] = f2bf(in[i]);
}

// ---------------------------------------------------------------------------
// K2 v9: char GRU, bf16 MFMA; U2 via 4 coalesced float4 loads (padded layout).
// 256 blocks x 1024 thr (16 waves), 16 words/block; wave wv owns cols
// [wv*16,+16) of all 3 gates. r,z weights register-resident; n streamed.
__global__ __launch_bounds__(1024, 1) void k_chargru(
    const int* __restrict__ chars, const float* __restrict__ U2p,
    const unsigned short* __restrict__ Wb, const float* __restrict__ bhh,
    float* __restrict__ char_h){
  __shared__ unsigned short hb[16][280];   // 9KB bf16 h
  __shared__ int chs_all[16][16];          // 1KB [w][t]
  const int tid  = threadIdx.x;
  const int lane = tid & 63;
  const int wv   = tid >> 6;        // 0..15
  const int la   = lane & 15;
  const int lb   = lane >> 4;       // 0..3
  const int w0   = blockIdx.x * 16;
  const int c    = wv*16 + la;      // this thread's h-column (0..255)
  bf16x8 wreg[2][8];
  #pragma unroll
  for(int g=0; g<2; g++){
    const int gcol = g*CHc + c;
    #pragma unroll
    for(int ks=0; ks<8; ks++)
      wreg[g][ks] = *reinterpret_cast<const bf16x8*>(
          &Wb[(size_t)gcol*CHc + ks*32 + lb*8]);
  }
  const unsigned short* wnp = &Wb[(size_t)(2*CHc + c)*CHc + lb*8];  // n-gate row
  const float bhn = bhh[2*CHc + c];
  float hfr[4];
  #pragma unroll
  for(int i=0;i<4;i++) hfr[i]=0.f;
  for(int f=tid; f<16*280; f+=1024) (&hb[0][0])[f] = 0;
  if(tid < 256) chs_all[tid>>4][tid&15] = chars[(size_t)(w0 + (tid>>4))*CCh + (tid&15)];
  __syncthreads();

  for(int t=0; t<CCh; t++){
    // ---- issue this step's 4 float4 U2 loads (consumed post-MFMA) ----
    float4 u2v[4];
    #pragma unroll
    for(int i=0;i<4;i++){
      const int ch = chs_all[lb*4 + i][t];
      u2v[i] = *reinterpret_cast<const float4*>(&U2p[(((size_t)ch*256) + c)*4]);
    }
    // ---- MFMA phase: r,z from regs; n streamed in 2 chunks of 4 ----
    f32x4 acc[3];
    #pragma unroll
    for(int g=0;g<3;g++) acc[g] = (f32x4){0.f,0.f,0.f,0.f};
    {
      bf16x8 wn[4];
      #pragma unroll
      for(int q=0;q<4;q++)
        wn[q] = *reinterpret_cast<const bf16x8*>(wnp + q*32);
      #pragma unroll
      for(int ks=0; ks<4; ks++){
        bf16x8 a = *reinterpret_cast<const bf16x8*>(&hb[la][ks*32 + lb*8]);
        acc[0] = __builtin_amdgcn_mfma_f32_16x16x32_bf16(a, wreg[0][ks], acc[0], 0,0,0);
        acc[1] = __builtin_amdgcn_mfma_f32_16x16x32_bf16(a, wreg[1][ks], acc[1], 0,0,0);
        acc[2] = __builtin_amdgcn_mfma_f32_16x16x32_bf16(a, wn[ks],      acc[2], 0,0,0);
      }
      #pragma unroll
      for(int q=0;q<4;q++)
        wn[q] = *reinterpret_cast<const bf16x8*>(wnp + (4+q)*32);
      #pragma unroll
      for(int ks=4; ks<8; ks++){
        bf16x8 a = *reinterpret_cast<const bf16x8*>(&hb[la][ks*32 + lb*8]);
        acc[0] = __builtin_amdgcn_mfma_f32_16x16x32_bf16(a, wreg[0][ks], acc[0], 0,0,0);
        acc[1] = __builtin_amdgcn_mfma_f32_16x16x32_bf16(a, wreg[1][ks], acc[1], 0,0,0);
        acc[2] = __builtin_amdgcn_mfma_f32_16x16x32_bf16(a, wn[ks-4],    acc[2], 0,0,0);
      }
    }
    __syncthreads();   // hb reads done (epilogue overwrites hb)
    // ---- register epilogue ----
    #pragma unroll
    for(int i=0;i<4;i++){
      const int w = lb*4 + i;
      float r = sigmoidf_(u2v[i].x + acc[0][i]);
      float z = sigmoidf_(u2v[i].y + acc[1][i]);
      float n = tanhf_   (u2v[i].z + r*(acc[2][i] + bhn));
      float hn = (1.f - z)*n + z*hfr[i];
      hfr[i] = hn;
      hb[w][c] = f2bf(hn);
    }
    __syncthreads();   // hb ready for next step
  }
  #pragma unroll
  for(int i=0;i<4;i++){
    const int w = lb*4 + i;
    char_h[(size_t)(w0+w)*CHc + c] = hfr[i];
  }
}

// ---------------------------------------------------------------------------
// K3a: pack A = [concat(wemb[x[tok]], chh[tok])] -> bf16 [4096][768]
__global__ __launch_bounds__(256) void k_abf(
    const int* __restrict__ x, const float* __restrict__ wemb,
    const float* __restrict__ chh, unsigned short* __restrict__ Abf){
  const int tok = blockIdx.x;
  const int tid = threadIdx.x;
  const int wid = x[tok];
  #pragma unroll
  for(int i=0;i<3;i++){
    int k = i*256 + tid;
    float v = (k < EE) ? wemb[(size_t)wid*EE + k] : chh[(size_t)tok*CHc + (k-EE)];
    Abf[(size_t)tok*KIN + k] = f2bf(v);
  }
}

// ---------------------------------------------------------------------------
// K3b: gx GEMM via bf16 MFMA. M=4096 N=1536 K=768, 64x64 tiles, 4 waves.
// Fragment scheme = chargru's verified mapping (A m=la, D row=(l>>4)*4+i).
// B-frags direct from bf16 gWih (rows k-contiguous, L2-hot).
// bias folded (+bhh for r,z gates). Output f32 gx[token][g].
__global__ __launch_bounds__(256) void k_gxmfma(
    const unsigned short* __restrict__ Abf, const unsigned short* __restrict__ Wbih,
    const float* __restrict__ bih, const float* __restrict__ bhh,
    float* __restrict__ gx){
  __shared__ unsigned short As[64][136];   // 17.4KB (272B rows, 16B-aligned)
  const int tid  = threadIdx.x;
  const int lane = tid & 63;
  const int wv   = tid >> 6;        // 0..3
  const int la   = lane & 15;
  const int lb   = lane >> 4;       // 0..3
  const int rb   = blockIdx.x * 64;
  const int nb   = blockIdx.y * 64;
  const int g    = nb + wv*16 + la; // this thread's output col
  f32x4 acc[4];
  #pragma unroll
  for(int mt=0;mt<4;mt++) acc[mt] = (f32x4){0.f,0.f,0.f,0.f};
  for(int kc=0; kc<6; kc++){
    // stage As[64][128] bf16
    #pragma unroll
    for(int i=0;i<4;i++){
      int idx = i*256 + tid;
      int row = idx >> 4, ck = idx & 15;
      *reinterpret_cast<uint4*>(&As[row][ck*8]) =
          *reinterpret_cast<const uint4*>(&Abf[(size_t)(rb+row)*KIN + kc*128 + ck*8]);
    }
    __syncthreads();
    #pragma unroll
    for(int ks=0; ks<4; ks++){
      bf16x8 b = *reinterpret_cast<const bf16x8*>(
          &Wbih[(size_t)g*KIN + kc*128 + ks*32 + lb*8]);
      #pragma unroll
      for(int mt=0;mt<4;mt++){
        bf16x8 a = *reinterpret_cast<const bf16x8*>(&As[mt*16 + la][ks*32 + lb*8]);
        acc[mt] = __builtin_amdgcn_mfma_f32_16x16x32_bf16(a, b, acc[mt], 0,0,0);
      }
    }
    __syncthreads();
  }
  const float bias = bih[g] + (g < 2*HHm ? bhh[g] : 0.f);
  #pragma unroll
  for(int mt=0;mt<4;mt++)
    #pragma unroll
    for(int i=0;i<4;i++){
      int row = rb + mt*16 + lb*4 + i;
      gx[(size_t)row*G3H + g] = acc[mt][i] + bias;
    }
}

// ---------------------------------------------------------------------------
// K4 v6x: main GRU, tag-packed h exchange + pipelined poll (round-10 code)
// + XCD-LOCAL swizzle: bb = blockIdx&7 -> all 32 producers/consumers of a
// batch-slice land on one XCD (round-robin heuristic; correctness-neutral).
__global__ __launch_bounds__(512) void k_grumain(
    const float* __restrict__ Whh, const float* __restrict__ gx,
    const float* __restrict__ bhh, float* __restrict__ outh,
    unsigned long long* __restrict__ hx){
  __shared__ float hsh[8][516];      // 16.5KB
  __shared__ float red[3][8][16][9]; // 13.8KB
  const int tid  = threadIdx.x;
  const int lane = tid & 63;
  const int kw   = tid >> 6;
  const int jp   = lane & 15;
  const int bq   = lane >> 4;
  const int jb   = blockIdx.x >> 3;   // 0..31
  const int bb   = blockIdx.x & 7;    // 0..7  (same-bb blocks share an XCD)
  const int jglob = jb*16 + jp;
  const int kbase = kw*64 + bq*16;
  float4 wreg[3][4];
  #pragma unroll
  for(int g=0; g<3; g++)
    #pragma unroll
    for(int q=0; q<4; q++)
      wreg[g][q] = *reinterpret_cast<const float4*>(
          &Whh[((size_t)g*HHm + jglob)*HHm + kbase + q*4]);
  const int fb  = tid >> 4;
  const int fj  = tid & 15;
  const int fjg = jb*16 + fj;
  const int fbg = bb*8 + fb;
  const float fbhn = bhh[2*HHm + fjg];

  for(int t=0; t<TT; t++){
    float gxr=0.f, gxz=0.f, gxn=0.f;
    if(tid < 128){
      const size_t tok = (size_t)fbg*TT + t;
      gxr = gx[tok*G3H +           fjg];
      gxz = gx[tok*G3H + HHm +     fjg];
      gxn = gx[tok*G3H + 2*HHm +   fjg];
    }
    if(t > 0){
      const unsigned int want = (unsigned int)t;
      const size_t sbase = (size_t)((t-1)&1)*BB*HHm;
      const unsigned long long* p[8];
      unsigned long long v[8];
      #pragma unroll
      for(int i=0;i<8;i++){
        int f = i*512 + tid;
        int b = f >> 9, k = f & 511;
        p[i] = &hx[sbase + (size_t)(bb*8+b)*HHm + k];
        v[i] = __hip_atomic_load(p[i], __ATOMIC_RELAXED, __HIP_MEMORY_SCOPE_AGENT);
      }
      #pragma unroll
      for(int i=0;i<8;i++){
        while((unsigned int)(v[i]>>32) != want){
          __builtin_amdgcn_s_sleep(1);
          v[i] = __hip_atomic_load(p[i], __ATOMIC_RELAXED, __HIP_MEMORY_SCOPE_AGENT);
        }
        int f = i*512 + tid;
        int b = f >> 9, k = f & 511;
        hsh[b][k] = __uint_as_float((unsigned int)v[i]);
      }
      __syncthreads();
      float aR[8], aZ[8], aN[8];
      #pragma unroll
      for(int b=0;b<8;b++){ aR[b]=0.f; aZ[b]=0.f; aN[b]=0.f; }
      #pragma unroll
      for(int b=0; b<8; b++){
        float4 h0 = *reinterpret_cast<const float4*>(&hsh[b][kbase+0]);
        float4 h1 = *reinterpret_cast<const float4*>(&hsh[b][kbase+4]);
        float4 h2 = *reinterpret_cast<const float4*>(&hsh[b][kbase+8]);
        float4 h3 = *reinterpret_cast<const float4*>(&hsh[b][kbase+12]);
        aR[b] = fmaf(h0.x,wreg[0][0].x, fmaf(h0.y,wreg[0][0].y, fmaf(h0.z,wreg[0][0].z, fmaf(h0.w,wreg[0][0].w, aR[b]))));
        aR[b] = fmaf(h1.x,wreg[0][1].x, fmaf(h1.y,wreg[0][1].y, fmaf(h1.z,wreg[0][1].z, fmaf(h1.w,wreg[0][1].w, aR[b]))));
        aR[b] = fmaf(h2.x,wreg[0][2].x, fmaf(h2.y,wreg[0][2].y, fmaf(h2.z,wreg[0][2].z, fmaf(h2.w,wreg[0][2].w, aR[b]))));
        aR[b] = fmaf(h3.x,wreg[0][3].x, fmaf(h3.y,wreg[0][3].y, fmaf(h3.z,wreg[0][3].z, fmaf(h3.w,wreg[0][3].w, aR[b]))));
        aZ[b] = fmaf(h0.x,wreg[1][0].x, fmaf(h0.y,wreg[1][0].y, fmaf(h0.z,wreg[1][0].z, fmaf(h0.w,wreg[1][0].w, aZ[b]))));
        aZ[b] = fmaf(h1.x,wreg[1][1].x, fmaf(h1.y,wreg[1][1].y, fmaf(h1.z,wreg[1][1].z, fmaf(h1.w,wreg[1][1].w, aZ[b]))));
        aZ[b] = fmaf(h2.x,wreg[1][2].x, fmaf(h2.y,wreg[1][2].y, fmaf(h2.z,wreg[1][2].z, fmaf(h2.w,wreg[1][2].w, aZ[b]))));
        aZ[b] = fmaf(h3.x,wreg[1][3].x, fmaf(h3.y,wreg[1][3].y, fmaf(h3.z,wreg[1][3].z, fmaf(h3.w,wreg[1][3].w, aZ[b]))));
        aN[b] = fmaf(h0.x,wreg[2][0].x, fmaf(h0.y,wreg[2][0].y, fmaf(h0.z,wreg[2][0].z, fmaf(h0.w,wreg[2][0].w, aN[b]))));
        aN[b] = fmaf(h1.x,wreg[2][1].x, fmaf(h1.y,wreg[2][1].y, fmaf(h1.z,wreg[2][1].z, fmaf(h1.w,wreg[2][1].w, aN[b]))));
        aN[b] = fmaf(h2.x,wreg[2][2].x, fmaf(h2.y,wreg[2][2].y, fmaf(h2.z,wreg[2][2].z, fmaf(h2.w,wreg[2][2].w, aN[b]))));
        aN[b] = fmaf(h3.x,wreg[2][3].x, fmaf(h3.y,wreg[2][3].y, fmaf(h3.z,wreg[2][3].z, fmaf(h3.w,wreg[2][3].w, aN[b]))));
      }
      #pragma unroll
      for(int b=0;b<8;b++){
        aR[b] += __shfl_xor(aR[b], 16, 64); aR[b] += __shfl_xor(aR[b], 32, 64);
        aZ[b] += __shfl_xor(aZ[b], 16, 64); aZ[b] += __shfl_xor(aZ[b], 32, 64);
        aN[b] += __shfl_xor(aN[b], 16, 64); aN[b] += __shfl_xor(aN[b], 32, 64);
      }
      #pragma unroll
      for(int i=0;i<2;i++){
        int b = bq*2 + i;
        red[0][b][jp][kw] = aR[b];
        red[1][b][jp][kw] = aZ[b];
        red[2][b][jp][kw] = aN[b];
      }
      __syncthreads();
    }
    if(tid < 128){
      float sR=0.f, sZ=0.f, sN=0.f, hold=0.f;
      if(t > 0){
        #pragma unroll
        for(int w=0; w<8; w++){
          sR += red[0][fb][fj][w];
          sZ += red[1][fb][fj][w];
          sN += red[2][fb][fj][w];
        }
        hold = hsh[fb][fjg];
      }
      float rg = sigmoidf_(gxr + sR);
      float zg = sigmoidf_(gxz + sZ);
      float ng = tanhf_   (gxn + rg*(sN + fbhn));
      float hnew = (1.f - zg)*ng + zg*hold;
      outh[((size_t)t*BB + fbg)*HHm + fjg] = hnew;   // f32 for k_cls
      unsigned long long pv = ((unsigned long long)(unsigned int)(t+1) << 32)
                              | (unsigned long long)__float_as_uint(hnew);
      __hip_atomic_store(&hx[(size_t)(t&1)*BB*HHm + (size_t)fbg*HHm + fjg], pv,
                         __ATOMIC_RELAXED, __HIP_MEMORY_SCOPE_AGENT);
    }
    __syncthreads();
  }
}

// ---------------------------------------------------------------------------
// K5: classifier. One block per time-step t; reads outh[t][b][j].
__global__ __launch_bounds__(256) void k_cls(
    const float* __restrict__ outh, const float* __restrict__ clsW,
    const float* __restrict__ clsb, float* __restrict__ out){
  __shared__ float wls[20*HHm];     // 40KB
  __shared__ float hch[64][129];    // 33KB
  const int tid = threadIdx.x;
  const int t = blockIdx.x;
  const int b = tid & 63;
  const int q = tid >> 6;
  const int c0 = q*5;
  for(int f = tid*4; f < 20*HHm; f += 1024){
    float4 v = make_float4(0.f,0.f,0.f,0.f);
    if(f < NCLS*HHm) v = *reinterpret_cast<const float4*>(&clsW[f]);
    *reinterpret_cast<float4*>(&wls[f]) = v;
  }
  float acc[5] = {0.f,0.f,0.f,0.f,0.f};
  for(int kc=0; kc<4; kc++){
    __syncthreads();
    for(int i=0;i<32;i++){
      int f = i*256 + tid;
      int b2 = f >> 7, kk = f & 127;
      hch[b2][kk] = outh[((size_t)t*BB + b2)*HHm + kc*128 + kk];
    }
    __syncthreads();
    for(int k=0;k<128;k++){
      float hv = hch[b][k];
      #pragma unroll
      for(int i=0;i<5;i++)
        acc[i] = fmaf(hv, wls[(size_t)(c0+i)*HHm + kc*128 + k], acc[i]);
    }
  }
  #pragma unroll
  for(int i=0;i<5;i++){
    int cls = c0 + i;
    if(cls < NCLS) out[((size_t)b*TT + t)*NCLS + cls] = acc[i] + clsb[cls];
  }
}

// ---------------------------------------------------------------------------
extern "C" void kernel_launch(void* const* d_in, const int* in_sizes, int n_in,
                              void* d_out, int out_size, void* d_ws, size_t ws_size,
                              hipStream_t stream){
  const int*   x     = (const int*)d_in[0];
  const int*   chars = (const int*)d_in[1];
  const float* wemb  = (const float*)d_in[2];
  const float* cemb  = (const float*)d_in[3];
  const float* cWih  = (const float*)d_in[4];
  const float* cWhh  = (const float*)d_in[5];
  const float* cbih  = (const float*)d_in[6];
  const float* cbhh  = (const float*)d_in[7];
  const float* gWih  = (const float*)d_in[8];
  const float* gWhh  = (const float*)d_in[9];
  const float* gbih  = (const float*)d_in[10];
  const float* gbhh  = (const float*)d_in[11];
  const float* clsW  = (const float*)d_in[12];
  const float* clsb  = (const float*)d_in[13];
  float* out = (float*)d_out;
  float* ws  = (float*)d_ws;

  // workspace layout (floats unless noted)
  float* U2p   = ws;                   // 100*256*4  = 102400
  float* chh   = U2p + 102400;         // 4096*256   = 1048576
  float* gx    = chh + 1048576;        // 4096*1536  = 6291456   [token][g]
  float* outh  = gx + 6291456;         // 64*64*512  = 2097152   [t][b][j]
  unsigned long long* hx = (unsigned long long*)(outh + 2097152); // 2*64*512 u64
  unsigned short* Wb   = (unsigned short*)(hx + 2*BB*HHm);  // 768*256 bf16 (char Whh)
  unsigned short* Wbih = Wb + G3C*CHc;                      // 1536*768 bf16 (gWih)
  unsigned short* Abf  = (unsigned short*)outh;             // alias: used only pre-grumain

  k_uchar<<<CVOC, G3C, 0, stream>>>(cemb, cWih, cbih, cbhh, U2p);
  k_w2bf<<<(G3C*CHc + 255)/256, 256, 0, stream>>>(cWhh, Wb, G3C*CHc);
  k_w2bf<<<(G3H*KIN + 255)/256, 256, 0, stream>>>(gWih, Wbih, G3H*KIN);
  k_chargru<<<NTOK/16, 1024, 0, stream>>>(chars, U2p, Wb, cbhh, chh);
  k_abf<<<NTOK, 256, 0, stream>>>(x, wemb, chh, Abf);
  k_gxmfma<<<dim3(NTOK/64, G3H/64), 256, 0, stream>>>(Abf, Wbih, gbih, gbhh, gx);
  k_grumain<<<256, 512, 0, stream>>>(gWhh, gx, gbhh, outh, hx);
  k_cls<<<TT, 256, 0, stream>>>(outh, clsW, clsb, out);
}